// Round 13
// baseline (4037.026 us; speedup 1.0000x reference)
//
#include <hip/hip_runtime.h>
#include <math.h>

#define DEV_INLINE __device__ __forceinline__

constexpr int B = 32, S = 128, H = 1024, V = 32000, T = 50, L = 3;
constexpr int H2 = 2 * H, H4 = 4 * H;
constexpr int BH = B * H;
constexpr int MTOT = T * B;  // 1600 logits rows

// ---- d_out layout (floats): logits (B,T,V) | hT (L,B,H) | cT (L,B,H) | attn (B,T,S)
constexpr size_t HT_OFF   = (size_t)B * T * V;
constexpr size_t CT_OFF   = HT_OFF + (size_t)L * B * H;
constexpr size_t ATTN_OFF = CT_OFF + (size_t)L * B * H;

// ---- workspace layout (float units; bf16 buffers consume half-slots)
constexpr size_t WS_UKEYS = 0;                                  // B*S*H f32
constexpr size_t WS_EMBBF = WS_UKEYS + (size_t)B * S * H;       // T*BH ushort
constexpr size_t WS_H2ALL = WS_EMBBF + (size_t)T * BH / 2;      // T*BH f32
constexpr size_t WS_H     = WS_H2ALL + (size_t)T * BH;          // L*BH f32
constexpr size_t WS_C     = WS_H + (size_t)L * BH;              // L*BH f32
constexpr size_t WS_QWA   = WS_C + (size_t)L * BH;              // BH f32
constexpr size_t WS_SCO   = WS_QWA + (size_t)BH;                // B*S f32 (fallback)
constexpr size_t WS_GAT   = WS_SCO + (size_t)B * S;             // B*H4 f32 (fallback)
constexpr size_t WS_HBF   = WS_GAT + (size_t)B * H4;            // 2 banks L*BH ushort
constexpr size_t WS_XCBF  = WS_HBF + (size_t)2 * L * BH / 2;    // B*H2 ushort
constexpr size_t WS_OLALL = WS_XCBF + (size_t)B * H2 / 2;       // T*BH ushort
constexpr size_t WS_WBF   = WS_OLALL + (size_t)T * BH / 2;      // = 7,966,720 f

// bf16 weight region offsets (ushort units from WS_WBF base); fcw stays f32 (lazy cvt)
constexpr size_t OW_WA   = 0;
constexpr size_t OW_WIH0 = OW_WA   + (size_t)H * H;
constexpr size_t OW_WHH0 = OW_WIH0 + (size_t)H4 * H2;
constexpr size_t OW_WIH1 = OW_WHH0 + (size_t)H4 * H;
constexpr size_t OW_WHH1 = OW_WIH1 + (size_t)H4 * H;
constexpr size_t OW_WIH2 = OW_WHH1 + (size_t)H4 * H;
constexpr size_t OW_WHH2 = OW_WIH2 + (size_t)H4 * H;
constexpr size_t OW_END  = OW_WHH2 + (size_t)H4 * H;            // 30,408,704 ushort
constexpr size_t NEED_WS_BYTES = WS_WBF * 4 + OW_END * 2;       // well under r12's proven fit

typedef __attribute__((ext_vector_type(8))) short short8;
typedef __attribute__((ext_vector_type(4))) float f32x4;
typedef __attribute__((ext_vector_type(4))) unsigned short u16x4;

DEV_INLINE float sigmoidf_(float x) { return 1.f / (1.f + expf(-x)); }

// fast tanh: 1 - 2/(e^{2x}+1). NaN-safe: e->inf => 1, e->0 => -1. ~8 cycles.
DEV_INLINE float ftanh(float x) {
  float e = __expf(2.f * x);
  return 1.f - 2.f / (e + 1.f);
}

DEV_INLINE unsigned short bf16u(float f) {  // RNE f32->bf16 bits
  union { float f; unsigned u; } v; v.f = f;
  unsigned r = v.u + 0x7fffu + ((v.u >> 16) & 1u);
  return (unsigned short)(r >> 16);
}

DEV_INLINE float wave_sum(float v) {
#pragma unroll
  for (int o = 32; o; o >>= 1) v += __shfl_xor(v, o, 64);
  return v;
}

DEV_INLINE float blk_sum256(float v, float* buf) {
  v = wave_sum(v);
  __syncthreads();
  if ((threadIdx.x & 63) == 0) buf[threadIdx.x >> 6] = v;
  __syncthreads();
  return buf[0] + buf[1] + buf[2] + buf[3];
}

DEV_INLINE float blk_sum1024(float v, float* buf) {  // 16 waves
  v = wave_sum(v);
  __syncthreads();
  if ((threadIdx.x & 63) == 0) buf[threadIdx.x >> 6] = v;
  __syncthreads();
  float s = 0.f;
#pragma unroll
  for (int i = 0; i < 16; ++i) s += buf[i];
  return s;
}

// ---------------------------------------------------------------- state copies
__global__ void k_init(const float* __restrict__ h0, const float* __restrict__ c0,
                       float* __restrict__ hst, float* __restrict__ cst,
                       unsigned short* __restrict__ hbf) {
  int idx = blockIdx.x * 256 + threadIdx.x;
  if (idx < L * BH) { hst[idx] = h0[idx]; hbf[idx] = bf16u(h0[idx]); }
  else cst[idx - L * BH] = c0[idx - L * BH];
}

__global__ void k_fin(const float* __restrict__ hst, const float* __restrict__ h2src,
                      const float* __restrict__ cst, float* __restrict__ out) {
  int idx = blockIdx.x * 256 + threadIdx.x;
  if (idx < 2 * BH) out[HT_OFF + idx] = hst[idx];
  else if (idx < 3 * BH) out[HT_OFF + idx] = h2src[idx - 2 * BH];
  else out[HT_OFF + idx] = cst[idx - 3 * BH];
}

// -------------- one-shot f32 -> bf16 conversion of 7 weight regions (fcw lazy)
constexpr int NCVT = 7;
struct CvtArgs { const float* src[NCVT]; unsigned short* dst[NCVT]; };
constexpr int CV_N4[NCVT] = {
  H * H / 4, H4 * H2 / 4, H4 * H / 4, H4 * H / 4, H4 * H / 4,
  H4 * H / 4, H4 * H / 4};
__global__ void k_cvt_all(CvtArgs a) {
  int cum[NCVT + 1]; cum[0] = 0;
#pragma unroll
  for (int r = 0; r < NCVT; ++r) cum[r + 1] = cum[r] + CV_N4[r];
  const int total = cum[NCVT];
  int i = blockIdx.x * 256 + threadIdx.x;
  const int stride = gridDim.x * 256;
  for (; i < total; i += stride) {
    int r = 0;
#pragma unroll
    for (int q = 0; q < NCVT; ++q) r += (i >= cum[q + 1]) ? 1 : 0;
    int off = i - cum[r];
    f32x4 v = *(const f32x4*)(a.src[r] + (size_t)off * 4);
    u16x4 o;
    o[0] = bf16u(v[0]); o[1] = bf16u(v[1]); o[2] = bf16u(v[2]); o[3] = bf16u(v[3]);
    *(u16x4*)(a.dst[r] + (size_t)off * 4) = o;
  }
}

// --------------- Ukeys = enc @ Ua^T + ub via MFMA (f32 in, cvt-in-staging, f32 out)
__global__ __launch_bounds__(512) void k_ukeys_mfma(
    const float* __restrict__ X, const float* __restrict__ W,
    const float* __restrict__ bias, float* __restrict__ C) {
  __shared__ unsigned short As[128][72];
  __shared__ unsigned short Bs[128][72];
  const int tid = threadIdx.x, lane = tid & 63, wid = tid >> 6;
  const int wm = wid >> 2, wn = wid & 3;
  const int n0 = blockIdx.x * 128, m0 = blockIdx.y * 128;
  const int fr = lane & 15, kg = lane >> 4;
  f32x4 acc[4][2];
#pragma unroll
  for (int i = 0; i < 4; ++i)
#pragma unroll
    for (int j = 0; j < 2; ++j) acc[i][j] = {0.f, 0.f, 0.f, 0.f};
  for (int k0 = 0; k0 < H; k0 += 64) {
    __syncthreads();
#pragma unroll
    for (int r = 0; r < 4; ++r) {
      int i = tid + 512 * r;
      int row = i >> 4, c4 = (i & 15) * 4;
      f32x4 v = *(const f32x4*)(X + (size_t)(m0 + row) * H + k0 + c4);
      u16x4 o;
      o[0] = bf16u(v[0]); o[1] = bf16u(v[1]); o[2] = bf16u(v[2]); o[3] = bf16u(v[3]);
      *(u16x4*)&As[row][c4] = o;
    }
#pragma unroll
    for (int r = 0; r < 4; ++r) {
      int i = tid + 512 * r;
      int row = i >> 4, c4 = (i & 15) * 4;
      f32x4 v = *(const f32x4*)(W + (size_t)(n0 + row) * H + k0 + c4);
      u16x4 o;
      o[0] = bf16u(v[0]); o[1] = bf16u(v[1]); o[2] = bf16u(v[2]); o[3] = bf16u(v[3]);
      *(u16x4*)&Bs[row][c4] = o;
    }
    __syncthreads();
#pragma unroll
    for (int kk = 0; kk < 64; kk += 32) {
      short8 av[4], bv[2];
#pragma unroll
      for (int fm = 0; fm < 4; ++fm)
        av[fm] = *(const short8*)&As[wm * 64 + fm * 16 + fr][kk + kg * 8];
#pragma unroll
      for (int fn = 0; fn < 2; ++fn)
        bv[fn] = *(const short8*)&Bs[wn * 32 + fn * 16 + fr][kk + kg * 8];
#pragma unroll
      for (int fm = 0; fm < 4; ++fm)
#pragma unroll
        for (int fn = 0; fn < 2; ++fn)
          acc[fm][fn] = __builtin_amdgcn_mfma_f32_16x16x32_bf16(av[fm], bv[fn],
                                                                acc[fm][fn], 0, 0, 0);
    }
  }
#pragma unroll
  for (int fm = 0; fm < 4; ++fm)
#pragma unroll
    for (int fn = 0; fn < 2; ++fn)
#pragma unroll
      for (int r = 0; r < 4; ++r) {
        int m = m0 + wm * 64 + fm * 16 + kg * 4 + r;
        int n = n0 + wn * 32 + fn * 16 + fr;
        C[(size_t)m * H + n] = acc[fm][fn][r] + bias[n];
      }
}

// ------------------------------------------------- f32 Ukeys (fallback only)
__global__ __launch_bounds__(256) void k_gemm_nt(
    const float* __restrict__ A, const float* __restrict__ Bw,
    const float* __restrict__ bias, float* __restrict__ C, int N, int K) {
  __shared__ float As[16][132];
  __shared__ float Bs[16][68];
  const int i0 = blockIdx.y * 128, j0 = blockIdx.x * 64;
  const int ty = threadIdx.x >> 4, tx = threadIdx.x & 15;
  float acc[8][4] = {};
  for (int k0 = 0; k0 < K; k0 += 16) {
#pragma unroll
    for (int r = 0; r < 8; ++r) {
      int i = threadIdx.x + 256 * r;
      int mm = i >> 4, kk = i & 15;
      As[kk][mm] = A[(size_t)(i0 + mm) * K + k0 + kk];
    }
#pragma unroll
    for (int r = 0; r < 4; ++r) {
      int i = threadIdx.x + 256 * r;
      int nn = i >> 4, kk = i & 15;
      Bs[kk][nn] = Bw[(size_t)(j0 + nn) * K + k0 + kk];
    }
    __syncthreads();
#pragma unroll
    for (int kk = 0; kk < 16; ++kk) {
      float a[8], bb[4];
#pragma unroll
      for (int i = 0; i < 8; ++i) a[i] = As[kk][ty * 8 + i];
#pragma unroll
      for (int j = 0; j < 4; ++j) bb[j] = Bs[kk][tx * 4 + j];
#pragma unroll
      for (int i = 0; i < 8; ++i)
#pragma unroll
        for (int j = 0; j < 4; ++j) acc[i][j] = fmaf(a[i], bb[j], acc[i][j]);
    }
    __syncthreads();
  }
#pragma unroll
  for (int i = 0; i < 8; ++i) {
    size_t row = (size_t)(i0 + ty * 8 + i) * N;
#pragma unroll
    for (int j = 0; j < 4; ++j) {
      int col = j0 + tx * 4 + j;
      C[row + col] = acc[i][j] + bias[col];
    }
  }
}

// --------------------------------------- emb_all[t,b,:] = LN(embedding[tok]) -> bf16
__global__ void k_embln(const float* __restrict__ table, const int* __restrict__ target,
                        const float* __restrict__ g, const float* __restrict__ bta,
                        unsigned short* __restrict__ out) {
  __shared__ float rbuf[4];
  int idx = blockIdx.x;  // t*B + b
  int t = idx >> 5, b = idx & 31;
  int tok = (t == 0) ? 0 : target[b * T + (t - 1)];
  const float* e = table + (size_t)tok * H;
  int tid = threadIdx.x;
  float x[4];
#pragma unroll
  for (int r = 0; r < 4; ++r) x[r] = e[r * 256 + tid];
  float m = blk_sum256(x[0] + x[1] + x[2] + x[3], rbuf) * (1.f / H);
  float vs = 0.f;
#pragma unroll
  for (int r = 0; r < 4; ++r) { float d = x[r] - m; vs += d * d; }
  float var = blk_sum256(vs, rbuf) * (1.f / H);
  float rstd = rsqrtf(var + 1e-5f);
  unsigned short* o = out + (size_t)idx * H;
#pragma unroll
  for (int r = 0; r < 4; ++r) {
    int h = r * 256 + tid;
    o[h] = bf16u((x[r] - m) * rstd * g[h] + bta[h]);
  }
}

// -------- FUSED attention: scores(fast-tanh) + softmax + attn + ctx + LN + xcat
// one block per batch b, 1024 threads (16 waves). f32 ukeys/enc (r12 numerics).
__global__ __launch_bounds__(1024) void k_att(
    const float* __restrict__ qwa, const float* __restrict__ ukeys,
    const float* __restrict__ enc, const unsigned short* __restrict__ embt,
    const float* __restrict__ va, const float* __restrict__ vb,
    const float* __restrict__ temp, const int* __restrict__ vlen,
    const float* __restrict__ g, const float* __restrict__ bta,
    unsigned short* __restrict__ xbf, float* __restrict__ attn, int t) {
  __shared__ float sco_s[S];
  __shared__ float sw[S];
  __shared__ float rbuf[16];
  const int b = blockIdx.x, tid = threadIdx.x;
  const int lane = tid & 63, w = tid >> 6;
  // phase A: scores. wave w handles s = w*8..w*8+7; lane owns k = lane*16..+15
  float qR[16], vaR[16];
  {
    const float* qp = qwa + (size_t)b * H + lane * 16;
    const float* vp = va + lane * 16;
#pragma unroll
    for (int j = 0; j < 16; ++j) { qR[j] = qp[j]; vaR[j] = vp[j]; }
  }
#pragma unroll
  for (int i = 0; i < 8; ++i) {
    int s = w * 8 + i;
    const float* up = ukeys + ((size_t)(b * S + s)) * H + lane * 16;
    float a = 0.f;
#pragma unroll
    for (int j = 0; j < 16; ++j) a = fmaf(vaR[j], ftanh(qR[j] + up[j]), a);
    a = wave_sum(a);
    if (lane == 0) sco_s[s] = a;
  }
  __syncthreads();
  // phase B: softmax (first wave) + attn write
  if (tid < 64) {
    float vbv = vb[0], tmp = temp[0];
    int vl = vlen[b];
    float v0 = (sco_s[tid] + vbv) / tmp;
    float v1 = (sco_s[64 + tid] + vbv) / tmp;
    if (tid >= vl) v0 = -1e9f;
    if (64 + tid >= vl) v1 = -1e9f;
    float m = fmaxf(v0, v1);
#pragma unroll
    for (int o = 32; o; o >>= 1) m = fmaxf(m, __shfl_xor(m, o, 64));
    float e0 = expf(v0 - m), e1 = expf(v1 - m);
    float ssum = wave_sum(e0 + e1);
    float inv = 1.f / ssum;
    sw[tid] = e0 * inv;
    sw[64 + tid] = e1 * inv;
  }
  __syncthreads();
  if (tid < S) attn[((size_t)b * T + t) * S + tid] = sw[tid];
  // phase C: ctx, thread owns col h = tid (coalesced: stride-H rows)
  float v = 0.f;
  {
    const float* ep = enc + (size_t)b * S * H + tid;
#pragma unroll 4
    for (int s2 = 0; s2 < S; ++s2) v = fmaf(sw[s2], ep[(size_t)s2 * H], v);
  }
  // phase D: LN over 1024 cols
  float m = blk_sum1024(v, rbuf) * (1.f / H);
  float d = v - m;
  float var = blk_sum1024(d * d, rbuf) * (1.f / H);
  float rstd = rsqrtf(var + 1e-5f);
  // phase E: write xcat = [emb | ctxn]
  unsigned short* xr = xbf + (size_t)b * H2;
  xr[H + tid] = bf16u(d * rstd * g[tid] + bta[tid]);
  xr[tid] = embt[(size_t)b * H + tid];
}

// ------------------------------------------------------- attention scores (fallback)
__global__ void k_scores(const float* __restrict__ qwa, const float* __restrict__ ukeys,
                         const float* __restrict__ va, const float* __restrict__ vb,
                         const float* __restrict__ temp, const int* __restrict__ vlen,
                         float* __restrict__ sco) {
  int lane = threadIdx.x & 63, wid = threadIdx.x >> 6;
  int idx = blockIdx.x * 4 + wid;  // b*S + s
  int b = idx >> 7, s = idx & 127;
  const float* uk = ukeys + (size_t)idx * H;
  const float* q = qwa + (size_t)b * H;
  float a = 0.f;
#pragma unroll
  for (int i = 0; i < 16; ++i) {
    int k = i * 64 + lane;
    a = fmaf(va[k], tanhf(q[k] + uk[k]), a);
  }
  a = wave_sum(a);
  if (lane == 0) {
    float val = (a + vb[0]) / temp[0];
    if (s >= vlen[b]) val = -1e9f;
    sco[idx] = val;
  }
}

// ------ softmax + attn + ctx + LN + xcat (fallback)
__global__ void k_smctx(const float* __restrict__ sco, const float* __restrict__ enc,
                        const unsigned short* __restrict__ embt, const float* __restrict__ g,
                        const float* __restrict__ bta, unsigned short* __restrict__ xbf,
                        float* __restrict__ attn, int t) {
  __shared__ float sw[S];
  __shared__ float rbuf[4];
  int b = blockIdx.x, tid = threadIdx.x;
  if (tid < 64) {
    float v0 = sco[b * S + tid], v1 = sco[b * S + 64 + tid];
    float m = fmaxf(v0, v1);
#pragma unroll
    for (int o = 32; o; o >>= 1) m = fmaxf(m, __shfl_xor(m, o, 64));
    float e0 = expf(v0 - m), e1 = expf(v1 - m);
    float ssum = wave_sum(e0 + e1);
    float inv = 1.f / ssum;
    sw[tid] = e0 * inv;
    sw[64 + tid] = e1 * inv;
  }
  __syncthreads();
  if (tid < S) attn[((size_t)b * T + t) * S + tid] = sw[tid];
  float v[4] = {0.f, 0.f, 0.f, 0.f};
  for (int s2 = 0; s2 < S; ++s2) {
    float wv = sw[s2];
    const float* er = enc + ((size_t)b * S + s2) * H;
#pragma unroll
    for (int r = 0; r < 4; ++r) v[r] = fmaf(wv, er[r * 256 + tid], v[r]);
  }
  float m = blk_sum256(v[0] + v[1] + v[2] + v[3], rbuf) * (1.f / H);
  float vs = 0.f;
#pragma unroll
  for (int r = 0; r < 4; ++r) { float d = v[r] - m; vs += d * d; }
  float var = blk_sum256(vs, rbuf) * (1.f / H);
  float rstd = rsqrtf(var + 1e-5f);
  unsigned short* xr = xbf + (size_t)b * H2;
#pragma unroll
  for (int r = 0; r < 4; ++r) {
    int h = r * 256 + tid;
    xr[H + h] = bf16u((v[r] - m) * rstd * g[h] + bta[h]);
    xr[h] = embt[(size_t)b * H + h];
  }
}

// ----------------------------------------------------- MFMA skinny GEMM (bf16 W)
__global__ __launch_bounds__(256) void k_skinny_bf(
    const unsigned short* __restrict__ x, const unsigned short* __restrict__ Wb, int K,
    const float* __restrict__ bias, float* __restrict__ out, int obstride) {
  __shared__ float red[4][32][16];
  const int lane = threadIdx.x & 63, wid = threadIdx.x >> 6;
  const int jb = blockIdx.x * 16;
  const int jl = lane & 15, kg = lane >> 4;
  f32x4 acc0 = {0.f, 0.f, 0.f, 0.f}, acc1 = {0.f, 0.f, 0.f, 0.f};
  const int per = (K >> 5) >> 2;
  const int send = (wid + 1) * per;
  for (int s = wid * per; s < send; ++s) {
    const int ke = s * 32 + kg * 8;
    short8 bw = *(const short8*)(Wb + (size_t)(jb + jl) * K + ke);
    short8 a0 = *(const short8*)(x + (size_t)jl * K + ke);
    short8 a1 = *(const short8*)(x + (size_t)(16 + jl) * K + ke);
    acc0 = __builtin_amdgcn_mfma_f32_16x16x32_bf16(a0, bw, acc0, 0, 0, 0);
    acc1 = __builtin_amdgcn_mfma_f32_16x16x32_bf16(a1, bw, acc1, 0, 0, 0);
  }
#pragma unroll
  for (int r = 0; r < 4; ++r) {
    red[wid][kg * 4 + r][jl] = acc0[r];
    red[wid][16 + kg * 4 + r][jl] = acc1[r];
  }
  __syncthreads();
  const int tid = threadIdx.x;
#pragma unroll
  for (int u = 0; u < 2; ++u) {
    int oi = tid * 2 + u;
    int m = oi >> 4, j = oi & 15;
    float v = red[0][m][j] + red[1][m][j] + red[2][m][j] + red[3][m][j];
    int jg = jb + j;
    out[(size_t)m * obstride + jg] = v + bias[jg];
  }
}

// ---------- fused gate GEMM + LSTM cell, j-tile 4, all gates packed (256 blocks)
__global__ __launch_bounds__(256) void k_gates4(
    const unsigned short* __restrict__ x1, int K1,
    const unsigned short* __restrict__ x2, int K2,
    const unsigned short* __restrict__ W1, const unsigned short* __restrict__ W2,
    const float* __restrict__ bih, const float* __restrict__ bhh,
    float* __restrict__ cl, float* __restrict__ hl, unsigned short* __restrict__ hbfw) {
  __shared__ float red[4][32][17];
  const int lane = threadIdx.x & 63, wid = threadIdx.x >> 6;
  const int jb = blockIdx.x * 4;
  const int fr = lane & 15, kg = lane >> 4;
  const int wrow = (fr >> 2) * H + jb + (fr & 3);
  f32x4 acc0 = {0.f, 0.f, 0.f, 0.f}, acc1 = {0.f, 0.f, 0.f, 0.f};
  const int s1 = K1 >> 5, s2 = K2 >> 5;
  const int per = (s1 + s2) >> 2;
  const int sbeg = wid * per, send = sbeg + per;
  const int e1 = send < s1 ? send : s1;
#pragma unroll 4
  for (int s = sbeg; s < e1; ++s) {
    const int ke = s * 32 + kg * 8;
    short8 bw = *(const short8*)(W1 + (size_t)wrow * K1 + ke);
    short8 a0 = *(const short8*)(x1 + (size_t)fr * K1 + ke);
    short8 a1 = *(const short8*)(x1 + (size_t)(16 + fr) * K1 + ke);
    acc0 = __builtin_amdgcn_mfma_f32_16x16x32_bf16(a0, bw, acc0, 0, 0, 0);
    acc1 = __builtin_amdgcn_mfma_f32_16x16x32_bf16(a1, bw, acc1, 0, 0, 0);
  }
  const int b2 = sbeg > s1 ? sbeg : s1;
#pragma unroll 4
  for (int s = b2; s < send; ++s) {
    const int ke = (s - s1) * 32 + kg * 8;
    short8 bw = *(const short8*)(W2 + (size_t)wrow * K2 + ke);
    short8 a0 = *(const short8*)(x2 + (size_t)fr * K2 + ke);
    short8 a1 = *(const short8*)(x2 + (size_t)(16 + fr) * K2 + ke);
    acc0 = __builtin_amdgcn_mfma_f32_16x16x32_bf16(a0, bw, acc0, 0, 0, 0);
    acc1 = __builtin_amdgcn_mfma_f32_16x16x32_bf16(a1, bw, acc1, 0, 0, 0);
  }
#pragma unroll
  for (int r = 0; r < 4; ++r) {
    red[wid][kg * 4 + r][fr] = acc0[r];
    red[wid][16 + kg * 4 + r][fr] = acc1[r];
  }
  __syncthreads();
  const int tid = threadIdx.x;
  if (tid < 128) {
    int m = tid >> 2, jj = tid & 3, kcol = jb + jj;
    float gate[4];
#pragma unroll
    for (int g = 0; g < 4; ++g) {
      int f = g * 4 + jj;
      gate[g] = red[0][m][f] + red[1][m][f] + red[2][m][f] + red[3][m][f]
              + bih[g * H + kcol] + bhh[g * H + kcol];
    }
    int idx = m * H + kcol;
    float cn = sigmoidf_(gate[1]) * cl[idx] + sigmoidf_(gate[0]) * tanhf(gate[2]);
    float hn = sigmoidf_(gate[3]) * tanhf(cn);
    cl[idx] = cn;
    hl[idx] = hn;
    hbfw[idx] = bf16u(hn);
  }
}

// ------------------------------- batch LN of all h2 rows -> olbf_all (bf16)
__global__ void k_ln_all(const float* __restrict__ h2all, const float* __restrict__ g,
                         const float* __restrict__ bta, unsigned short* __restrict__ olbf) {
  __shared__ float rbuf[4];
  int row = blockIdx.x, tid = threadIdx.x;
  const float* hr = h2all + (size_t)row * H;
  float hv[4];
#pragma unroll
  for (int r = 0; r < 4; ++r) hv[r] = hr[r * 256 + tid];
  float m = blk_sum256(hv[0] + hv[1] + hv[2] + hv[3], rbuf) * (1.f / H);
  float vs = 0.f;
#pragma unroll
  for (int r = 0; r < 4; ++r) { float d = hv[r] - m; vs += d * d; }
  float var = blk_sum256(vs, rbuf) * (1.f / H);
  float rstd = rsqrtf(var + 1e-5f);
  unsigned short* o = olbf + (size_t)row * H;
#pragma unroll
  for (int r = 0; r < 4; ++r) {
    int k = r * 256 + tid;
    o[k] = bf16u((hv[r] - m) * rstd * g[k] + bta[k]);
  }
}

// -------------------- logits GEMM: X[1600x1024]bf16 @ fcw[32000x1024]f32^T + b
// fcw converted to bf16 during LDS staging (saves the one-time 64MB cvt pass).
__global__ __launch_bounds__(512) void k_logits(
    const unsigned short* __restrict__ X, const float* __restrict__ W,
    const float* __restrict__ bias, float* __restrict__ out) {
  __shared__ unsigned short As[128][72];
  __shared__ unsigned short Bs[128][72];
  const int tid = threadIdx.x, lane = tid & 63, wid = tid >> 6;
  const int wm = wid >> 2, wn = wid & 3;
  const int n0 = blockIdx.x * 128, m0 = blockIdx.y * 128;
  const int fr = lane & 15, kg = lane >> 4;
  f32x4 acc[4][2];
#pragma unroll
  for (int i = 0; i < 4; ++i)
#pragma unroll
    for (int j = 0; j < 2; ++j) acc[i][j] = {0.f, 0.f, 0.f, 0.f};
  const short8 zero8 = {0, 0, 0, 0, 0, 0, 0, 0};
  for (int k0 = 0; k0 < H; k0 += 64) {
    __syncthreads();
#pragma unroll
    for (int r = 0; r < 2; ++r) {  // stage A (bf16 in)
      int i = tid + 512 * r, row = i >> 3, c8 = (i & 7) * 8;
      int gm = m0 + row;
      short8 v = (gm < MTOT) ? *(const short8*)(X + (size_t)gm * H + k0 + c8) : zero8;
      *(short8*)&As[row][c8] = v;
    }
#pragma unroll
    for (int r = 0; r < 4; ++r) {  // stage B (f32 -> bf16)
      int i = tid + 512 * r;
      int row = i >> 4, c4 = (i & 15) * 4;
      f32x4 v = *(const f32x4*)(W + (size_t)(n0 + row) * H + k0 + c4);
      u16x4 o;
      o[0] = bf16u(v[0]); o[1] = bf16u(v[1]); o[2] = bf16u(v[2]); o[3] = bf16u(v[3]);
      *(u16x4*)&Bs[row][c4] = o;
    }
    __syncthreads();
#pragma unroll
    for (int kk = 0; kk < 64; kk += 32) {
      short8 av[4], bv[2];
#pragma unroll
      for (int fm = 0; fm < 4; ++fm)
        av[fm] = *(const short8*)&As[wm * 64 + fm * 16 + fr][kk + kg * 8];
#pragma unroll
      for (int fn = 0; fn < 2; ++fn)
        bv[fn] = *(const short8*)&Bs[wn * 32 + fn * 16 + fr][kk + kg * 8];
#pragma unroll
      for (int fm = 0; fm < 4; ++fm)
#pragma unroll
        for (int fn = 0; fn < 2; ++fn)
          acc[fm][fn] = __builtin_amdgcn_mfma_f32_16x16x32_bf16(av[fm], bv[fn],
                                                                acc[fm][fn], 0, 0, 0);
    }
  }
#pragma unroll
  for (int fm = 0; fm < 4; ++fm)
#pragma unroll
    for (int fn = 0; fn < 2; ++fn)
#pragma unroll
      for (int r = 0; r < 4; ++r) {
        int m = m0 + wm * 64 + fm * 16 + kg * 4 + r;
        if (m < MTOT) {
          int n = n0 + wn * 32 + fn * 16 + fr;
          int b = m & 31, t = m >> 5;
          out[((size_t)b * T + t) * V + n] = acc[fm][fn][r] + bias[n];
        }
      }
}

// ================= fallback (round-3) kernels: f32 W converted in-register ==
__global__ __launch_bounds__(256) void k_mfma_skinny(
    const unsigned short* __restrict__ x1, const float* __restrict__ W1, int K1,
    const unsigned short* __restrict__ x2, const float* __restrict__ W2, int K2,
    const float* __restrict__ b1, const float* __restrict__ b2,
    float* __restrict__ out, int obstride) {
  __shared__ float red[4][32][16];
  const int lane = threadIdx.x & 63, wid = threadIdx.x >> 6;
  const int jb = blockIdx.x * 16;
  const int jl = lane & 15, kg = lane >> 4;
  f32x4 acc0 = {0.f, 0.f, 0.f, 0.f}, acc1 = {0.f, 0.f, 0.f, 0.f};
  const int s1 = K1 >> 5, s2 = K2 >> 5;
  const int per = (s1 + s2) >> 2;
  const int send = (wid + 1) * per;
  for (int s = wid * per; s < send; ++s) {
    const unsigned short* x; const float* W; int K, k0;
    if (s < s1) { x = x1; W = W1; K = K1; k0 = s * 32; }
    else       { x = x2; W = W2; K = K2; k0 = (s - s1) * 32; }
    const int ke = k0 + kg * 8;
    const float* wp = W + (size_t)(jb + jl) * K + ke;
    f32x4 w0 = *(const f32x4*)wp;
    f32x4 w1 = *(const f32x4*)(wp + 4);
    short8 bw;
    bw[0] = (short)bf16u(w0[0]); bw[1] = (short)bf16u(w0[1]);
    bw[2] = (short)bf16u(w0[2]); bw[3] = (short)bf16u(w0[3]);
    bw[4] = (short)bf16u(w1[0]); bw[5] = (short)bf16u(w1[1]);
    bw[6] = (short)bf16u(w1[2]); bw[7] = (short)bf16u(w1[3]);
    short8 a0 = *(const short8*)(x + (size_t)jl * K + ke);
    short8 a1 = *(const short8*)(x + (size_t)(16 + jl) * K + ke);
    acc0 = __builtin_amdgcn_mfma_f32_16x16x32_bf16(a0, bw, acc0, 0, 0, 0);
    acc1 = __builtin_amdgcn_mfma_f32_16x16x32_bf16(a1, bw, acc1, 0, 0, 0);
  }
#pragma unroll
  for (int r = 0; r < 4; ++r) {
    red[wid][kg * 4 + r][jl] = acc0[r];
    red[wid][16 + kg * 4 + r][jl] = acc1[r];
  }
  __syncthreads();
  const int tid = threadIdx.x;
#pragma unroll
  for (int u = 0; u < 2; ++u) {
    int oi = tid * 2 + u;
    int m = oi >> 4, j = oi & 15;
    float v = red[0][m][j] + red[1][m][j] + red[2][m][j] + red[3][m][j];
    int jg = jb + j;
    v += (b1 ? b1[jg] : 0.f) + (b2 ? b2[jg] : 0.f);
    out[(size_t)m * obstride + jg] = v;
  }
}

__global__ void k_cell(const float* __restrict__ gat, float* __restrict__ cl,
                       float* __restrict__ hl, unsigned short* __restrict__ hbf) {
  int idx = blockIdx.x * 256 + threadIdx.x;
  int b = idx >> 10, k = idx & 1023;
  const float* gb = gat + (size_t)b * H4;
  float i_ = gb[k], f_ = gb[H + k], g_ = gb[2 * H + k], o_ = gb[3 * H + k];
  float cn = sigmoidf_(f_) * cl[idx] + sigmoidf_(i_) * tanhf(g_);
  float hn = sigmoidf_(o_) * tanhf(cn);
  cl[idx] = cn;
  hl[idx] = hn;
  hbf[idx] = bf16u(hn);
}

__global__ void k_cell2ln(const float* __restrict__ gat, float* __restrict__ cl,
                          float* __restrict__ hl, const float* __restrict__ g,
                          const float* __restrict__ bta, unsigned short* __restrict__ olbf,
                          unsigned short* __restrict__ hbf) {
  __shared__ float rbuf[4];
  int b = blockIdx.x, tid = threadIdx.x;
  const float* gb = gat + (size_t)b * H4;
  float hv[4];
#pragma unroll
  for (int r = 0; r < 4; ++r) {
    int k = r * 256 + tid;
    float i_ = gb[k], f_ = gb[H + k], g_ = gb[2 * H + k], o_ = gb[3 * H + k];
    float cn = sigmoidf_(f_) * cl[b * H + k] + sigmoidf_(i_) * tanhf(g_);
    float hn = sigmoidf_(o_) * tanhf(cn);
    cl[b * H + k] = cn;
    hl[b * H + k] = hn;
    hbf[b * H + k] = bf16u(hn);
    hv[r] = hn;
  }
  float m = blk_sum256(hv[0] + hv[1] + hv[2] + hv[3], rbuf) * (1.f / H);
  float vs = 0.f;
#pragma unroll
  for (int r = 0; r < 4; ++r) { float d = hv[r] - m; vs += d * d; }
  float var = blk_sum256(vs, rbuf) * (1.f / H);
  float rstd = rsqrtf(var + 1e-5f);
#pragma unroll
  for (int r = 0; r < 4; ++r) {
    int k = r * 256 + tid;
    olbf[b * H + k] = bf16u((hv[r] - m) * rstd * g[k] + bta[k]);
  }
}

// ---------------------------------------------------------------------------
extern "C" void kernel_launch(void* const* d_in, const int* in_sizes, int n_in,
                              void* d_out, int out_size, void* d_ws, size_t ws_size,
                              hipStream_t stream) {
  (void)in_sizes; (void)n_in; (void)out_size;
  const float* enc = (const float*)d_in[0];
  const float* h0 = (const float*)d_in[1];
  const float* c0 = (const float*)d_in[2];
  const int* vlen = (const int*)d_in[3];
  const int* target = (const int*)d_in[4];
  const float* emb_table = (const float*)d_in[5];
  const float* Wa = (const float*)d_in[6];
  const float* ba = (const float*)d_in[7];
  const float* Ua = (const float*)d_in[8];
  const float* ub = (const float*)d_in[9];
  const float* Va = (const float*)d_in[10];
  const float* vb = (const float*)d_in[11];
  const float* temp = (const float*)d_in[12];
  const float* Wih[3] = {(const float*)d_in[13], (const float*)d_in[17], (const float*)d_in[21]};
  const float* Whh[3] = {(const float*)d_in[14], (const float*)d_in[18], (const float*)d_in[22]};
  const float* bih[3] = {(const float*)d_in[15], (const float*)d_in[19], (const float*)d_in[23]};
  const float* bhh[3] = {(const float*)d_in[16], (const float*)d_in[20], (const float*)d_in[24]};
  const float* fcw = (const float*)d_in[25];
  const float* fcb = (const float*)d_in[26];
  const float* eng = (const float*)d_in[27];
  const float* enb = (const float*)d_in[28];
  const float* cng = (const float*)d_in[29];
  const float* cnb = (const float*)d_in[30];
  const float* ong = (const float*)d_in[31];
  const float* onb = (const float*)d_in[32];

  float* ws = (float*)d_ws;
  float* ukeys = ws + WS_UKEYS;
  unsigned short* embbf = (unsigned short*)(ws + WS_EMBBF);
  float* h2all = ws + WS_H2ALL;
  float* hst = ws + WS_H;
  float* cst = ws + WS_C;
  float* qwa = ws + WS_QWA;
  float* sco = ws + WS_SCO;
  float* gat = ws + WS_GAT;
  unsigned short* hbf = (unsigned short*)(ws + WS_HBF);  // 2 banks of L*BH
  unsigned short* xcbf = (unsigned short*)(ws + WS_XCBF);
  unsigned short* olall = (unsigned short*)(ws + WS_OLALL);
  unsigned short* wbf = (unsigned short*)(ws + WS_WBF);
  float* out = (float*)d_out;

  const bool big = ws_size >= NEED_WS_BYTES;

  k_init<<<768, 256, 0, stream>>>(h0, c0, hst, cst, hbf);
  k_embln<<<T * B, 256, 0, stream>>>(emb_table, target, eng, enb, embbf);

  if (big) {
    k_ukeys_mfma<<<dim3(H / 128, (B * S) / 128), 512, 0, stream>>>(enc, Ua, ub, ukeys);

    CvtArgs ca;
    ca.src[0] = Wa;      ca.dst[0] = wbf + OW_WA;
    ca.src[1] = Wih[0];  ca.dst[1] = wbf + OW_WIH0;
    ca.src[2] = Whh[0];  ca.dst[2] = wbf + OW_WHH0;
    ca.src[3] = Wih[1];  ca.dst[3] = wbf + OW_WIH1;
    ca.src[4] = Whh[1];  ca.dst[4] = wbf + OW_WHH1;
    ca.src[5] = Wih[2];  ca.dst[5] = wbf + OW_WIH2;
    ca.src[6] = Whh[2];  ca.dst[6] = wbf + OW_WHH2;
    k_cvt_all<<<2048, 256, 0, stream>>>(ca);

    for (int t = 0; t < T; ++t) {
      const unsigned short* rb = hbf + (size_t)(t & 1) * (L * BH);       // read bank
      unsigned short* wb = hbf + (size_t)((t + 1) & 1) * (L * BH);      // write bank
      k_skinny_bf<<<H / 16, 256, 0, stream>>>(rb + 2 * BH, wbf + OW_WA, H, ba, qwa, H);
      k_att<<<B, 1024, 0, stream>>>(qwa, ukeys, enc, embbf + (size_t)t * BH,
                                    Va, vb, temp, vlen, cng, cnb, xcbf,
                                    out + ATTN_OFF, t);
      k_gates4<<<H / 4, 256, 0, stream>>>(xcbf, H2, rb, H,
                                          wbf + OW_WIH0, wbf + OW_WHH0,
                                          bih[0], bhh[0], cst, hst, wb);
      k_gates4<<<H / 4, 256, 0, stream>>>(wb, H, rb + BH, H,
                                          wbf + OW_WIH1, wbf + OW_WHH1,
                                          bih[1], bhh[1], cst + BH, hst + BH, wb + BH);
      k_gates4<<<H / 4, 256, 0, stream>>>(wb + BH, H, rb + 2 * BH, H,
                                          wbf + OW_WIH2, wbf + OW_WHH2,
                                          bih[2], bhh[2], cst + 2 * BH,
                                          h2all + (size_t)t * BH, wb + 2 * BH);
    }
    k_ln_all<<<T * B, 256, 0, stream>>>(h2all, ong, onb, olall);
    k_logits<<<dim3(V / 128, (MTOT + 127) / 128), 512, 0, stream>>>(olall, fcw, fcb, out);
    k_fin<<<768, 256, 0, stream>>>(hst, h2all + (size_t)(T - 1) * BH, cst, out);
  } else {
    // fallback: f32 weights with in-register conversion (proven round-3 path)
    k_gemm_nt<<<dim3(H / 64, (B * S) / 128), 256, 0, stream>>>(enc, Ua, ub, ukeys, H, H);
    for (int t = 0; t < T; ++t) {
      k_mfma_skinny<<<H / 16, 256, 0, stream>>>(hbf + 2 * BH, Wa, H, nullptr, nullptr, 0,
                                                ba, nullptr, qwa, H);
      k_scores<<<(B * S) / 4, 256, 0, stream>>>(qwa, ukeys, Va, vb, temp, vlen, sco);
      k_smctx<<<B, 256, 0, stream>>>(sco, enc, embbf + (size_t)t * BH, cng, cnb, xcbf,
                                     out + ATTN_OFF, t);
      k_mfma_skinny<<<H4 / 16, 256, 0, stream>>>(xcbf, Wih[0], H2, hbf, Whh[0], H,
                                                 bih[0], bhh[0], gat, H4);
      k_cell<<<BH / 256, 256, 0, stream>>>(gat, cst, hst, hbf);
      k_mfma_skinny<<<H4 / 16, 256, 0, stream>>>(hbf, Wih[1], H, hbf + BH, Whh[1], H,
                                                 bih[1], bhh[1], gat, H4);
      k_cell<<<BH / 256, 256, 0, stream>>>(gat, cst + BH, hst + BH, hbf + BH);
      k_mfma_skinny<<<H4 / 16, 256, 0, stream>>>(hbf + BH, Wih[2], H, hbf + 2 * BH, Whh[2], H,
                                                 bih[2], bhh[2], gat, H4);
      k_cell2ln<<<B, 256, 0, stream>>>(gat, cst + 2 * BH, hst + 2 * BH, ong, onb,
                                       olall + (size_t)t * BH, hbf + 2 * BH);
      k_mfma_skinny<<<V / 16, 256, 0, stream>>>(olall + (size_t)t * BH, fcw, H,
                                                nullptr, nullptr, 0,
                                                fcb, nullptr, out + (size_t)t * V, T * V);
    }
    k_fin<<<768, 256, 0, stream>>>(hst, hst + 2 * BH, cst, out);
  }
}

// Round 14
// 3251.914 us; speedup vs baseline: 1.2414x; 1.2414x over previous
//
#include <hip/hip_runtime.h>
#include <math.h>

#define DEV_INLINE __device__ __forceinline__

constexpr int B = 32, S = 128, H = 1024, V = 32000, T = 50, L = 3;
constexpr int H2 = 2 * H, H4 = 4 * H;
constexpr int BH = B * H;
constexpr int MTOT = T * B;  // 1600 logits rows

// ---- d_out layout (floats): logits (B,T,V) | hT (L,B,H) | cT (L,B,H) | attn (B,T,S)
constexpr size_t HT_OFF   = (size_t)B * T * V;
constexpr size_t CT_OFF   = HT_OFF + (size_t)L * B * H;
constexpr size_t ATTN_OFF = CT_OFF + (size_t)L * B * H;

// ---- workspace layout (float units; bf16 buffers consume half-slots) — r11 proven
constexpr size_t WS_UKEYS = 0;                                  // B*S*H f32
constexpr size_t WS_EMBBF = WS_UKEYS + (size_t)B * S * H;       // T*BH ushort
constexpr size_t WS_H2ALL = WS_EMBBF + (size_t)T * BH / 2;      // T*BH f32
constexpr size_t WS_H     = WS_H2ALL + (size_t)T * BH;          // L*BH f32
constexpr size_t WS_C     = WS_H + (size_t)L * BH;              // L*BH f32
constexpr size_t WS_QWA   = WS_C + (size_t)L * BH;              // BH f32
constexpr size_t WS_SCO   = WS_QWA + (size_t)BH;                // B*S f32
constexpr size_t WS_GAT   = WS_SCO + (size_t)B * S;             // B*H4 f32 (fallback)
constexpr size_t WS_HBF   = WS_GAT + (size_t)B * H4;            // 2 banks L*BH ushort
constexpr size_t WS_XCBF  = WS_HBF + (size_t)2 * L * BH / 2;    // B*H2 ushort
constexpr size_t WS_OLALL = WS_XCBF + (size_t)B * H2 / 2;       // T*BH ushort
constexpr size_t WS_WBF   = WS_OLALL + (size_t)T * BH / 2;      // = 7,966,720 f

// bf16 weight region offsets (ushort units from WS_WBF base)
constexpr size_t OW_WA   = 0;
constexpr size_t OW_WIH0 = OW_WA   + (size_t)H * H;
constexpr size_t OW_WHH0 = OW_WIH0 + (size_t)H4 * H2;
constexpr size_t OW_WIH1 = OW_WHH0 + (size_t)H4 * H;
constexpr size_t OW_WHH1 = OW_WIH1 + (size_t)H4 * H;
constexpr size_t OW_WIH2 = OW_WHH1 + (size_t)H4 * H;
constexpr size_t OW_WHH2 = OW_WIH2 + (size_t)H4 * H;
constexpr size_t OW_FCW  = OW_WHH2 + (size_t)H4 * H;
constexpr size_t OW_END  = OW_FCW  + (size_t)V * H;             // 63,176,704 ushort
constexpr size_t NEED_WS_BYTES = WS_WBF * 4 + OW_END * 2;       // 158,220,288 (proven fit)

typedef __attribute__((ext_vector_type(8))) short short8;
typedef __attribute__((ext_vector_type(4))) float f32x4;
typedef __attribute__((ext_vector_type(4))) unsigned short u16x4;

DEV_INLINE float sigmoidf_(float x) { return 1.f / (1.f + expf(-x)); }

DEV_INLINE unsigned short bf16u(float f) {  // RNE f32->bf16 bits
  union { float f; unsigned u; } v; v.f = f;
  unsigned r = v.u + 0x7fffu + ((v.u >> 16) & 1u);
  return (unsigned short)(r >> 16);
}

DEV_INLINE float wave_sum(float v) {
#pragma unroll
  for (int o = 32; o; o >>= 1) v += __shfl_xor(v, o, 64);
  return v;
}

DEV_INLINE float blk_sum256(float v, float* buf) {
  v = wave_sum(v);
  __syncthreads();
  if ((threadIdx.x & 63) == 0) buf[threadIdx.x >> 6] = v;
  __syncthreads();
  return buf[0] + buf[1] + buf[2] + buf[3];
}

// ---------------------------------------------------------------- state copies
__global__ void k_init(const float* __restrict__ h0, const float* __restrict__ c0,
                       float* __restrict__ hst, float* __restrict__ cst,
                       unsigned short* __restrict__ hbf) {
  int idx = blockIdx.x * 256 + threadIdx.x;
  if (idx < L * BH) { hst[idx] = h0[idx]; hbf[idx] = bf16u(h0[idx]); }
  else cst[idx - L * BH] = c0[idx - L * BH];
}

__global__ void k_fin(const float* __restrict__ hst, const float* __restrict__ h2src,
                      const float* __restrict__ cst, float* __restrict__ out) {
  int idx = blockIdx.x * 256 + threadIdx.x;
  if (idx < 2 * BH) out[HT_OFF + idx] = hst[idx];
  else if (idx < 3 * BH) out[HT_OFF + idx] = h2src[idx - 2 * BH];
  else out[HT_OFF + idx] = cst[idx - 3 * BH];
}

// -------------- one-shot f32 -> bf16 conversion of ALL 8 weight regions
constexpr int NCVT = 8;
struct CvtArgs { const float* src[NCVT]; unsigned short* dst[NCVT]; };
constexpr int CV_N4[NCVT] = {
  H * H / 4, H4 * H2 / 4, H4 * H / 4, H4 * H / 4, H4 * H / 4,
  H4 * H / 4, H4 * H / 4, V * H / 4};
__global__ void k_cvt_all(CvtArgs a) {
  int cum[NCVT + 1]; cum[0] = 0;
#pragma unroll
  for (int r = 0; r < NCVT; ++r) cum[r + 1] = cum[r] + CV_N4[r];
  const int total = cum[NCVT];
  int i = blockIdx.x * 256 + threadIdx.x;
  const int stride = gridDim.x * 256;
  for (; i < total; i += stride) {
    int r = 0;
#pragma unroll
    for (int q = 0; q < NCVT; ++q) r += (i >= cum[q + 1]) ? 1 : 0;
    int off = i - cum[r];
    f32x4 v = *(const f32x4*)(a.src[r] + (size_t)off * 4);
    u16x4 o;
    o[0] = bf16u(v[0]); o[1] = bf16u(v[1]); o[2] = bf16u(v[2]); o[3] = bf16u(v[3]);
    *(u16x4*)(a.dst[r] + (size_t)off * 4) = o;
  }
}

// --------------- Ukeys = enc @ Ua^T + ub via MFMA (f32 in, cvt-in-staging, f32 out)
// tile 128(M) x 128(N) x 64(K); 512 thr = 8 waves (2M x 4N); same verified lane
// mapping as k_logits. M=4096, N=1024 exact multiples -> no guards.
__global__ __launch_bounds__(512) void k_ukeys_mfma(
    const float* __restrict__ X, const float* __restrict__ W,
    const float* __restrict__ bias, float* __restrict__ C) {
  __shared__ unsigned short As[128][72];
  __shared__ unsigned short Bs[128][72];
  const int tid = threadIdx.x, lane = tid & 63, wid = tid >> 6;
  const int wm = wid >> 2, wn = wid & 3;
  const int n0 = blockIdx.x * 128, m0 = blockIdx.y * 128;
  const int fr = lane & 15, kg = lane >> 4;
  f32x4 acc[4][2];
#pragma unroll
  for (int i = 0; i < 4; ++i)
#pragma unroll
    for (int j = 0; j < 2; ++j) acc[i][j] = {0.f, 0.f, 0.f, 0.f};
  for (int k0 = 0; k0 < H; k0 += 64) {
    __syncthreads();
#pragma unroll
    for (int r = 0; r < 4; ++r) {  // stage A: 128 rows x 64 k, f32 -> bf16
      int i = tid + 512 * r;        // 0..2047 groups of 4
      int row = i >> 4, c4 = (i & 15) * 4;
      f32x4 v = *(const f32x4*)(X + (size_t)(m0 + row) * H + k0 + c4);
      u16x4 o;
      o[0] = bf16u(v[0]); o[1] = bf16u(v[1]); o[2] = bf16u(v[2]); o[3] = bf16u(v[3]);
      *(u16x4*)&As[row][c4] = o;
    }
#pragma unroll
    for (int r = 0; r < 4; ++r) {  // stage B
      int i = tid + 512 * r;
      int row = i >> 4, c4 = (i & 15) * 4;
      f32x4 v = *(const f32x4*)(W + (size_t)(n0 + row) * H + k0 + c4);
      u16x4 o;
      o[0] = bf16u(v[0]); o[1] = bf16u(v[1]); o[2] = bf16u(v[2]); o[3] = bf16u(v[3]);
      *(u16x4*)&Bs[row][c4] = o;
    }
    __syncthreads();
#pragma unroll
    for (int kk = 0; kk < 64; kk += 32) {
      short8 av[4], bv[2];
#pragma unroll
      for (int fm = 0; fm < 4; ++fm)
        av[fm] = *(const short8*)&As[wm * 64 + fm * 16 + fr][kk + kg * 8];
#pragma unroll
      for (int fn = 0; fn < 2; ++fn)
        bv[fn] = *(const short8*)&Bs[wn * 32 + fn * 16 + fr][kk + kg * 8];
#pragma unroll
      for (int fm = 0; fm < 4; ++fm)
#pragma unroll
        for (int fn = 0; fn < 2; ++fn)
          acc[fm][fn] = __builtin_amdgcn_mfma_f32_16x16x32_bf16(av[fm], bv[fn],
                                                                acc[fm][fn], 0, 0, 0);
    }
  }
#pragma unroll
  for (int fm = 0; fm < 4; ++fm)
#pragma unroll
    for (int fn = 0; fn < 2; ++fn)
#pragma unroll
      for (int r = 0; r < 4; ++r) {
        int m = m0 + wm * 64 + fm * 16 + kg * 4 + r;
        int n = n0 + wn * 32 + fn * 16 + fr;
        C[(size_t)m * H + n] = acc[fm][fn][r] + bias[n];
      }
}

// ------------------------------------------------- f32 Ukeys (fallback only)
__global__ __launch_bounds__(256) void k_gemm_nt(
    const float* __restrict__ A, const float* __restrict__ Bw,
    const float* __restrict__ bias, float* __restrict__ C, int N, int K) {
  __shared__ float As[16][132];
  __shared__ float Bs[16][68];
  const int i0 = blockIdx.y * 128, j0 = blockIdx.x * 64;
  const int ty = threadIdx.x >> 4, tx = threadIdx.x & 15;
  float acc[8][4] = {};
  for (int k0 = 0; k0 < K; k0 += 16) {
#pragma unroll
    for (int r = 0; r < 8; ++r) {
      int i = threadIdx.x + 256 * r;
      int mm = i >> 4, kk = i & 15;
      As[kk][mm] = A[(size_t)(i0 + mm) * K + k0 + kk];
    }
#pragma unroll
    for (int r = 0; r < 4; ++r) {
      int i = threadIdx.x + 256 * r;
      int nn = i >> 4, kk = i & 15;
      Bs[kk][nn] = Bw[(size_t)(j0 + nn) * K + k0 + kk];
    }
    __syncthreads();
#pragma unroll
    for (int kk = 0; kk < 16; ++kk) {
      float a[8], bb[4];
#pragma unroll
      for (int i = 0; i < 8; ++i) a[i] = As[kk][ty * 8 + i];
#pragma unroll
      for (int j = 0; j < 4; ++j) bb[j] = Bs[kk][tx * 4 + j];
#pragma unroll
      for (int i = 0; i < 8; ++i)
#pragma unroll
        for (int j = 0; j < 4; ++j) acc[i][j] = fmaf(a[i], bb[j], acc[i][j]);
    }
    __syncthreads();
  }
#pragma unroll
  for (int i = 0; i < 8; ++i) {
    size_t row = (size_t)(i0 + ty * 8 + i) * N;
#pragma unroll
    for (int j = 0; j < 4; ++j) {
      int col = j0 + tx * 4 + j;
      C[row + col] = acc[i][j] + bias[col];
    }
  }
}

// --------------------------------------- emb_all[t,b,:] = LN(embedding[tok]) -> bf16
__global__ void k_embln(const float* __restrict__ table, const int* __restrict__ target,
                        const float* __restrict__ g, const float* __restrict__ bta,
                        unsigned short* __restrict__ out) {
  __shared__ float rbuf[4];
  int idx = blockIdx.x;  // t*B + b
  int t = idx >> 5, b = idx & 31;
  int tok = (t == 0) ? 0 : target[b * T + (t - 1)];
  const float* e = table + (size_t)tok * H;
  int tid = threadIdx.x;
  float x[4];
#pragma unroll
  for (int r = 0; r < 4; ++r) x[r] = e[r * 256 + tid];
  float m = blk_sum256(x[0] + x[1] + x[2] + x[3], rbuf) * (1.f / H);
  float vs = 0.f;
#pragma unroll
  for (int r = 0; r < 4; ++r) { float d = x[r] - m; vs += d * d; }
  float var = blk_sum256(vs, rbuf) * (1.f / H);
  float rstd = rsqrtf(var + 1e-5f);
  unsigned short* o = out + (size_t)idx * H;
#pragma unroll
  for (int r = 0; r < 4; ++r) {
    int h = r * 256 + tid;
    o[h] = bf16u((x[r] - m) * rstd * g[h] + bta[h]);
  }
}

// ------------------------------------------------------- attention scores (f32)
__global__ void k_scores(const float* __restrict__ qwa, const float* __restrict__ ukeys,
                         const float* __restrict__ va, const float* __restrict__ vb,
                         const float* __restrict__ temp, const int* __restrict__ vlen,
                         float* __restrict__ sco) {
  int lane = threadIdx.x & 63, wid = threadIdx.x >> 6;
  int idx = blockIdx.x * 4 + wid;  // b*S + s
  int b = idx >> 7, s = idx & 127;
  const float* uk = ukeys + (size_t)idx * H;
  const float* q = qwa + (size_t)b * H;
  float a = 0.f;
#pragma unroll
  for (int i = 0; i < 16; ++i) {
    int k = i * 64 + lane;
    a = fmaf(va[k], tanhf(q[k] + uk[k]), a);
  }
  a = wave_sum(a);
  if (lane == 0) {
    float val = (a + vb[0]) / temp[0];
    if (s >= vlen[b]) val = -1e9f;
    sco[idx] = val;
  }
}

// ------ softmax + attn write + ctx (f32 enc) + LN + build xcat_bf16 = [emb | ctxn]
__global__ void k_smctx(const float* __restrict__ sco, const float* __restrict__ enc,
                        const unsigned short* __restrict__ embt, const float* __restrict__ g,
                        const float* __restrict__ bta, unsigned short* __restrict__ xbf,
                        float* __restrict__ attn, int t) {
  __shared__ float sw[S];
  __shared__ float rbuf[4];
  int b = blockIdx.x, tid = threadIdx.x;
  if (tid < 64) {
    float v0 = sco[b * S + tid], v1 = sco[b * S + 64 + tid];
    float m = fmaxf(v0, v1);
#pragma unroll
    for (int o = 32; o; o >>= 1) m = fmaxf(m, __shfl_xor(m, o, 64));
    float e0 = expf(v0 - m), e1 = expf(v1 - m);
    float ssum = wave_sum(e0 + e1);
    float inv = 1.f / ssum;
    sw[tid] = e0 * inv;
    sw[64 + tid] = e1 * inv;
  }
  __syncthreads();
  if (tid < S) attn[((size_t)b * T + t) * S + tid] = sw[tid];
  float v[4] = {0.f, 0.f, 0.f, 0.f};
  for (int s2 = 0; s2 < S; ++s2) {
    float wv = sw[s2];
    const float* er = enc + ((size_t)b * S + s2) * H;
#pragma unroll
    for (int r = 0; r < 4; ++r) v[r] = fmaf(wv, er[r * 256 + tid], v[r]);
  }
  float m = blk_sum256(v[0] + v[1] + v[2] + v[3], rbuf) * (1.f / H);
  float vs = 0.f;
#pragma unroll
  for (int r = 0; r < 4; ++r) { float d = v[r] - m; vs += d * d; }
  float var = blk_sum256(vs, rbuf) * (1.f / H);
  float rstd = rsqrtf(var + 1e-5f);
  unsigned short* xr = xbf + (size_t)b * H2;
#pragma unroll
  for (int r = 0; r < 4; ++r) {
    int h = r * 256 + tid;
    xr[H + h] = bf16u((v[r] - m) * rstd * g[h] + bta[h]);
    xr[h] = embt[(size_t)b * H + h];
  }
}

// ----------------------------------------------------- MFMA skinny GEMM (bf16 W)
// used for qWa. out[m,j] = sum_k x[m,k]*Wb[j,k] + bias[j]. 16 j/block, 4 waves split K.
__global__ __launch_bounds__(256) void k_skinny_bf(
    const unsigned short* __restrict__ x, const unsigned short* __restrict__ Wb, int K,
    const float* __restrict__ bias, float* __restrict__ out, int obstride) {
  __shared__ float red[4][32][16];
  const int lane = threadIdx.x & 63, wid = threadIdx.x >> 6;
  const int jb = blockIdx.x * 16;
  const int jl = lane & 15, kg = lane >> 4;
  f32x4 acc0 = {0.f, 0.f, 0.f, 0.f}, acc1 = {0.f, 0.f, 0.f, 0.f};
  const int per = (K >> 5) >> 2;
  const int send = (wid + 1) * per;
  for (int s = wid * per; s < send; ++s) {
    const int ke = s * 32 + kg * 8;
    short8 bw = *(const short8*)(Wb + (size_t)(jb + jl) * K + ke);
    short8 a0 = *(const short8*)(x + (size_t)jl * K + ke);
    short8 a1 = *(const short8*)(x + (size_t)(16 + jl) * K + ke);
    acc0 = __builtin_amdgcn_mfma_f32_16x16x32_bf16(a0, bw, acc0, 0, 0, 0);
    acc1 = __builtin_amdgcn_mfma_f32_16x16x32_bf16(a1, bw, acc1, 0, 0, 0);
  }
#pragma unroll
  for (int r = 0; r < 4; ++r) {
    red[wid][kg * 4 + r][jl] = acc0[r];
    red[wid][16 + kg * 4 + r][jl] = acc1[r];
  }
  __syncthreads();
  const int tid = threadIdx.x;
#pragma unroll
  for (int u = 0; u < 2; ++u) {
    int oi = tid * 2 + u;
    int m = oi >> 4, j = oi & 15;
    float v = red[0][m][j] + red[1][m][j] + red[2][m][j] + red[3][m][j];
    int jg = jb + j;
    out[(size_t)m * obstride + jg] = v + bias[jg];
  }
}

// ---------- fused gate GEMM + LSTM cell, j-tile 4, all gates packed (256 blocks)
__global__ __launch_bounds__(256) void k_gates4(
    const unsigned short* __restrict__ x1, int K1,
    const unsigned short* __restrict__ x2, int K2,
    const unsigned short* __restrict__ W1, const unsigned short* __restrict__ W2,
    const float* __restrict__ bih, const float* __restrict__ bhh,
    float* __restrict__ cl, float* __restrict__ hl, unsigned short* __restrict__ hbfw) {
  __shared__ float red[4][32][17];
  const int lane = threadIdx.x & 63, wid = threadIdx.x >> 6;
  const int jb = blockIdx.x * 4;
  const int fr = lane & 15, kg = lane >> 4;
  const int wrow = (fr >> 2) * H + jb + (fr & 3);
  f32x4 acc0 = {0.f, 0.f, 0.f, 0.f}, acc1 = {0.f, 0.f, 0.f, 0.f};
  const int s1 = K1 >> 5, s2 = K2 >> 5;
  const int per = (s1 + s2) >> 2;
  const int sbeg = wid * per, send = sbeg + per;
  const int e1 = send < s1 ? send : s1;
#pragma unroll 4
  for (int s = sbeg; s < e1; ++s) {
    const int ke = s * 32 + kg * 8;
    short8 bw = *(const short8*)(W1 + (size_t)wrow * K1 + ke);
    short8 a0 = *(const short8*)(x1 + (size_t)fr * K1 + ke);
    short8 a1 = *(const short8*)(x1 + (size_t)(16 + fr) * K1 + ke);
    acc0 = __builtin_amdgcn_mfma_f32_16x16x32_bf16(a0, bw, acc0, 0, 0, 0);
    acc1 = __builtin_amdgcn_mfma_f32_16x16x32_bf16(a1, bw, acc1, 0, 0, 0);
  }
  const int b2 = sbeg > s1 ? sbeg : s1;
#pragma unroll 4
  for (int s = b2; s < send; ++s) {
    const int ke = (s - s1) * 32 + kg * 8;
    short8 bw = *(const short8*)(W2 + (size_t)wrow * K2 + ke);
    short8 a0 = *(const short8*)(x2 + (size_t)fr * K2 + ke);
    short8 a1 = *(const short8*)(x2 + (size_t)(16 + fr) * K2 + ke);
    acc0 = __builtin_amdgcn_mfma_f32_16x16x32_bf16(a0, bw, acc0, 0, 0, 0);
    acc1 = __builtin_amdgcn_mfma_f32_16x16x32_bf16(a1, bw, acc1, 0, 0, 0);
  }
#pragma unroll
  for (int r = 0; r < 4; ++r) {
    red[wid][kg * 4 + r][fr] = acc0[r];
    red[wid][16 + kg * 4 + r][fr] = acc1[r];
  }
  __syncthreads();
  const int tid = threadIdx.x;
  if (tid < 128) {
    int m = tid >> 2, jj = tid & 3, kcol = jb + jj;
    float gate[4];
#pragma unroll
    for (int g = 0; g < 4; ++g) {
      int f = g * 4 + jj;
      gate[g] = red[0][m][f] + red[1][m][f] + red[2][m][f] + red[3][m][f]
              + bih[g * H + kcol] + bhh[g * H + kcol];
    }
    int idx = m * H + kcol;
    float cn = sigmoidf_(gate[1]) * cl[idx] + sigmoidf_(gate[0]) * tanhf(gate[2]);
    float hn = sigmoidf_(gate[3]) * tanhf(cn);
    cl[idx] = cn;
    hl[idx] = hn;
    hbfw[idx] = bf16u(hn);
  }
}

// ------------------------------- batch LN of all h2 rows -> olbf_all (bf16)
__global__ void k_ln_all(const float* __restrict__ h2all, const float* __restrict__ g,
                         const float* __restrict__ bta, unsigned short* __restrict__ olbf) {
  __shared__ float rbuf[4];
  int row = blockIdx.x, tid = threadIdx.x;
  const float* hr = h2all + (size_t)row * H;
  float hv[4];
#pragma unroll
  for (int r = 0; r < 4; ++r) hv[r] = hr[r * 256 + tid];
  float m = blk_sum256(hv[0] + hv[1] + hv[2] + hv[3], rbuf) * (1.f / H);
  float vs = 0.f;
#pragma unroll
  for (int r = 0; r < 4; ++r) { float d = hv[r] - m; vs += d * d; }
  float var = blk_sum256(vs, rbuf) * (1.f / H);
  float rstd = rsqrtf(var + 1e-5f);
  unsigned short* o = olbf + (size_t)row * H;
#pragma unroll
  for (int r = 0; r < 4; ++r) {
    int k = r * 256 + tid;
    o[k] = bf16u((hv[r] - m) * rstd * g[k] + bta[k]);
  }
}

// -------------------- logits GEMM: X[1600x1024]bf16 @ W[32000x1024]^T + b
// tile 128(M) x 128(N) x 64(K); 512 thr = 8 waves (2M x 4N); wave tile 64x32.
__global__ __launch_bounds__(512) void k_logits(
    const unsigned short* __restrict__ X, const unsigned short* __restrict__ Wb,
    const float* __restrict__ bias, float* __restrict__ out) {
  __shared__ unsigned short As[128][72];
  __shared__ unsigned short Bs[128][72];
  const int tid = threadIdx.x, lane = tid & 63, wid = tid >> 6;
  const int wm = wid >> 2, wn = wid & 3;
  const int n0 = blockIdx.x * 128, m0 = blockIdx.y * 128;
  const int fr = lane & 15, kg = lane >> 4;
  f32x4 acc[4][2];
#pragma unroll
  for (int i = 0; i < 4; ++i)
#pragma unroll
    for (int j = 0; j < 2; ++j) acc[i][j] = {0.f, 0.f, 0.f, 0.f};
  const short8 zero8 = {0, 0, 0, 0, 0, 0, 0, 0};
  for (int k0 = 0; k0 < H; k0 += 64) {
    __syncthreads();
#pragma unroll
    for (int r = 0; r < 2; ++r) {
      int i = tid + 512 * r, row = i >> 3, c8 = (i & 7) * 8;
      int gm = m0 + row;
      short8 v = (gm < MTOT) ? *(const short8*)(X + (size_t)gm * H + k0 + c8) : zero8;
      *(short8*)&As[row][c8] = v;
    }
#pragma unroll
    for (int r = 0; r < 2; ++r) {
      int i = tid + 512 * r, row = i >> 3, c8 = (i & 7) * 8;
      *(short8*)&Bs[row][c8] = *(const short8*)(Wb + (size_t)(n0 + row) * H + k0 + c8);
    }
    __syncthreads();
#pragma unroll
    for (int kk = 0; kk < 64; kk += 32) {
      short8 av[4], bv[2];
#pragma unroll
      for (int fm = 0; fm < 4; ++fm)
        av[fm] = *(const short8*)&As[wm * 64 + fm * 16 + fr][kk + kg * 8];
#pragma unroll
      for (int fn = 0; fn < 2; ++fn)
        bv[fn] = *(const short8*)&Bs[wn * 32 + fn * 16 + fr][kk + kg * 8];
#pragma unroll
      for (int fm = 0; fm < 4; ++fm)
#pragma unroll
        for (int fn = 0; fn < 2; ++fn)
          acc[fm][fn] = __builtin_amdgcn_mfma_f32_16x16x32_bf16(av[fm], bv[fn],
                                                                acc[fm][fn], 0, 0, 0);
    }
  }
#pragma unroll
  for (int fm = 0; fm < 4; ++fm)
#pragma unroll
    for (int fn = 0; fn < 2; ++fn)
#pragma unroll
      for (int r = 0; r < 4; ++r) {
        int m = m0 + wm * 64 + fm * 16 + kg * 4 + r;
        if (m < MTOT) {
          int n = n0 + wn * 32 + fn * 16 + fr;
          int b = m & 31, t = m >> 5;
          out[((size_t)b * T + t) * V + n] = acc[fm][fn][r] + bias[n];
        }
      }
}

// ================= fallback (round-3) kernels: f32 W converted in-register ==
__global__ __launch_bounds__(256) void k_mfma_skinny(
    const unsigned short* __restrict__ x1, const float* __restrict__ W1, int K1,
    const unsigned short* __restrict__ x2, const float* __restrict__ W2, int K2,
    const float* __restrict__ b1, const float* __restrict__ b2,
    float* __restrict__ out, int obstride) {
  __shared__ float red[4][32][16];
  const int lane = threadIdx.x & 63, wid = threadIdx.x >> 6;
  const int jb = blockIdx.x * 16;
  const int jl = lane & 15, kg = lane >> 4;
  f32x4 acc0 = {0.f, 0.f, 0.f, 0.f}, acc1 = {0.f, 0.f, 0.f, 0.f};
  const int s1 = K1 >> 5, s2 = K2 >> 5;
  const int per = (s1 + s2) >> 2;
  const int send = (wid + 1) * per;
  for (int s = wid * per; s < send; ++s) {
    const unsigned short* x; const float* W; int K, k0;
    if (s < s1) { x = x1; W = W1; K = K1; k0 = s * 32; }
    else       { x = x2; W = W2; K = K2; k0 = (s - s1) * 32; }
    const int ke = k0 + kg * 8;
    const float* wp = W + (size_t)(jb + jl) * K + ke;
    f32x4 w0 = *(const f32x4*)wp;
    f32x4 w1 = *(const f32x4*)(wp + 4);
    short8 bw;
    bw[0] = (short)bf16u(w0[0]); bw[1] = (short)bf16u(w0[1]);
    bw[2] = (short)bf16u(w0[2]); bw[3] = (short)bf16u(w0[3]);
    bw[4] = (short)bf16u(w1[0]); bw[5] = (short)bf16u(w1[1]);
    bw[6] = (short)bf16u(w1[2]); bw[7] = (short)bf16u(w1[3]);
    short8 a0 = *(const short8*)(x + (size_t)jl * K + ke);
    short8 a1 = *(const short8*)(x + (size_t)(16 + jl) * K + ke);
    acc0 = __builtin_amdgcn_mfma_f32_16x16x32_bf16(a0, bw, acc0, 0, 0, 0);
    acc1 = __builtin_amdgcn_mfma_f32_16x16x32_bf16(a1, bw, acc1, 0, 0, 0);
  }
#pragma unroll
  for (int r = 0; r < 4; ++r) {
    red[wid][kg * 4 + r][jl] = acc0[r];
    red[wid][16 + kg * 4 + r][jl] = acc1[r];
  }
  __syncthreads();
  const int tid = threadIdx.x;
#pragma unroll
  for (int u = 0; u < 2; ++u) {
    int oi = tid * 2 + u;
    int m = oi >> 4, j = oi & 15;
    float v = red[0][m][j] + red[1][m][j] + red[2][m][j] + red[3][m][j];
    int jg = jb + j;
    v += (b1 ? b1[jg] : 0.f) + (b2 ? b2[jg] : 0.f);
    out[(size_t)m * obstride + jg] = v;
  }
}

__global__ void k_cell(const float* __restrict__ gat, float* __restrict__ cl,
                       float* __restrict__ hl, unsigned short* __restrict__ hbf) {
  int idx = blockIdx.x * 256 + threadIdx.x;
  int b = idx >> 10, k = idx & 1023;
  const float* gb = gat + (size_t)b * H4;
  float i_ = gb[k], f_ = gb[H + k], g_ = gb[2 * H + k], o_ = gb[3 * H + k];
  float cn = sigmoidf_(f_) * cl[idx] + sigmoidf_(i_) * tanhf(g_);
  float hn = sigmoidf_(o_) * tanhf(cn);
  cl[idx] = cn;
  hl[idx] = hn;
  hbf[idx] = bf16u(hn);
}

__global__ void k_cell2ln(const float* __restrict__ gat, float* __restrict__ cl,
                          float* __restrict__ hl, const float* __restrict__ g,
                          const float* __restrict__ bta, unsigned short* __restrict__ olbf,
                          unsigned short* __restrict__ hbf) {
  __shared__ float rbuf[4];
  int b = blockIdx.x, tid = threadIdx.x;
  const float* gb = gat + (size_t)b * H4;
  float hv[4];
#pragma unroll
  for (int r = 0; r < 4; ++r) {
    int k = r * 256 + tid;
    float i_ = gb[k], f_ = gb[H + k], g_ = gb[2 * H + k], o_ = gb[3 * H + k];
    float cn = sigmoidf_(f_) * cl[b * H + k] + sigmoidf_(i_) * tanhf(g_);
    float hn = sigmoidf_(o_) * tanhf(cn);
    cl[b * H + k] = cn;
    hl[b * H + k] = hn;
    hbf[b * H + k] = bf16u(hn);
    hv[r] = hn;
  }
  float m = blk_sum256(hv[0] + hv[1] + hv[2] + hv[3], rbuf) * (1.f / H);
  float vs = 0.f;
#pragma unroll
  for (int r = 0; r < 4; ++r) { float d = hv[r] - m; vs += d * d; }
  float var = blk_sum256(vs, rbuf) * (1.f / H);
  float rstd = rsqrtf(var + 1e-5f);
#pragma unroll
  for (int r = 0; r < 4; ++r) {
    int k = r * 256 + tid;
    olbf[b * H + k] = bf16u((hv[r] - m) * rstd * g[k] + bta[k]);
  }
}

// ---------------------------------------------------------------------------
extern "C" void kernel_launch(void* const* d_in, const int* in_sizes, int n_in,
                              void* d_out, int out_size, void* d_ws, size_t ws_size,
                              hipStream_t stream) {
  (void)in_sizes; (void)n_in; (void)out_size;
  const float* enc = (const float*)d_in[0];
  const float* h0 = (const float*)d_in[1];
  const float* c0 = (const float*)d_in[2];
  const int* vlen = (const int*)d_in[3];
  const int* target = (const int*)d_in[4];
  const float* emb_table = (const float*)d_in[5];
  const float* Wa = (const float*)d_in[6];
  const float* ba = (const float*)d_in[7];
  const float* Ua = (const float*)d_in[8];
  const float* ub = (const float*)d_in[9];
  const float* Va = (const float*)d_in[10];
  const float* vb = (const float*)d_in[11];
  const float* temp = (const float*)d_in[12];
  const float* Wih[3] = {(const float*)d_in[13], (const float*)d_in[17], (const float*)d_in[21]};
  const float* Whh[3] = {(const float*)d_in[14], (const float*)d_in[18], (const float*)d_in[22]};
  const float* bih[3] = {(const float*)d_in[15], (const float*)d_in[19], (const float*)d_in[23]};
  const float* bhh[3] = {(const float*)d_in[16], (const float*)d_in[20], (const float*)d_in[24]};
  const float* fcw = (const float*)d_in[25];
  const float* fcb = (const float*)d_in[26];
  const float* eng = (const float*)d_in[27];
  const float* enb = (const float*)d_in[28];
  const float* cng = (const float*)d_in[29];
  const float* cnb = (const float*)d_in[30];
  const float* ong = (const float*)d_in[31];
  const float* onb = (const float*)d_in[32];

  float* ws = (float*)d_ws;
  float* ukeys = ws + WS_UKEYS;
  unsigned short* embbf = (unsigned short*)(ws + WS_EMBBF);
  float* h2all = ws + WS_H2ALL;
  float* hst = ws + WS_H;
  float* cst = ws + WS_C;
  float* qwa = ws + WS_QWA;
  float* sco = ws + WS_SCO;
  float* gat = ws + WS_GAT;
  unsigned short* hbf = (unsigned short*)(ws + WS_HBF);  // 2 banks of L*BH
  unsigned short* xcbf = (unsigned short*)(ws + WS_XCBF);
  unsigned short* olall = (unsigned short*)(ws + WS_OLALL);
  unsigned short* wbf = (unsigned short*)(ws + WS_WBF);
  float* out = (float*)d_out;

  const bool big = ws_size >= NEED_WS_BYTES;

  k_init<<<768, 256, 0, stream>>>(h0, c0, hst, cst, hbf);
  k_embln<<<T * B, 256, 0, stream>>>(emb_table, target, eng, enb, embbf);

  if (big) {
    // Ukeys via MFMA (f32 in/out, cvt during staging): grid (8 N-blocks, 32 M-blocks)
    k_ukeys_mfma<<<dim3(H / 128, (B * S) / 128), 512, 0, stream>>>(enc, Ua, ub, ukeys);

    CvtArgs ca;
    ca.src[0] = Wa;      ca.dst[0] = wbf + OW_WA;
    ca.src[1] = Wih[0];  ca.dst[1] = wbf + OW_WIH0;
    ca.src[2] = Whh[0];  ca.dst[2] = wbf + OW_WHH0;
    ca.src[3] = Wih[1];  ca.dst[3] = wbf + OW_WIH1;
    ca.src[4] = Whh[1];  ca.dst[4] = wbf + OW_WHH1;
    ca.src[5] = Wih[2];  ca.dst[5] = wbf + OW_WIH2;
    ca.src[6] = Whh[2];  ca.dst[6] = wbf + OW_WHH2;
    ca.src[7] = fcw;     ca.dst[7] = wbf + OW_FCW;
    k_cvt_all<<<2048, 256, 0, stream>>>(ca);

    for (int t = 0; t < T; ++t) {
      const unsigned short* rb = hbf + (size_t)(t & 1) * (L * BH);       // read bank
      unsigned short* wb = hbf + (size_t)((t + 1) & 1) * (L * BH);      // write bank
      k_skinny_bf<<<H / 16, 256, 0, stream>>>(rb + 2 * BH, wbf + OW_WA, H, ba, qwa, H);
      k_scores<<<(B * S) / 4, 256, 0, stream>>>(qwa, ukeys, Va, vb, temp, vlen, sco);
      k_smctx<<<B, 256, 0, stream>>>(sco, enc, embbf + (size_t)t * BH, cng, cnb, xcbf,
                                     out + ATTN_OFF, t);
      k_gates4<<<H / 4, 256, 0, stream>>>(xcbf, H2, rb, H,
                                          wbf + OW_WIH0, wbf + OW_WHH0,
                                          bih[0], bhh[0], cst, hst, wb);
      k_gates4<<<H / 4, 256, 0, stream>>>(wb, H, rb + BH, H,
                                          wbf + OW_WIH1, wbf + OW_WHH1,
                                          bih[1], bhh[1], cst + BH, hst + BH, wb + BH);
      k_gates4<<<H / 4, 256, 0, stream>>>(wb + BH, H, rb + 2 * BH, H,
                                          wbf + OW_WIH2, wbf + OW_WHH2,
                                          bih[2], bhh[2], cst + 2 * BH,
                                          h2all + (size_t)t * BH, wb + 2 * BH);
    }
    k_ln_all<<<T * B, 256, 0, stream>>>(h2all, ong, onb, olall);
    k_logits<<<dim3(V / 128, (MTOT + 127) / 128), 512, 0, stream>>>(olall, wbf + OW_FCW,
                                                                    fcb, out);
    k_fin<<<768, 256, 0, stream>>>(hst, h2all + (size_t)(T - 1) * BH, cst, out);
  } else {
    // fallback: f32 weights with in-register conversion (proven round-3 path)
    k_gemm_nt<<<dim3(H / 64, (B * S) / 128), 256, 0, stream>>>(enc, Ua, ub, ukeys, H, H);
    for (int t = 0; t < T; ++t) {
      k_mfma_skinny<<<H / 16, 256, 0, stream>>>(hbf + 2 * BH, Wa, H, nullptr, nullptr, 0,
                                                ba, nullptr, qwa, H);
      k_scores<<<(B * S) / 4, 256, 0, stream>>>(qwa, ukeys, Va, vb, temp, vlen, sco);
      k_smctx<<<B, 256, 0, stream>>>(sco, enc, embbf + (size_t)t * BH, cng, cnb, xcbf,
                                     out + ATTN_OFF, t);
      k_mfma_skinny<<<H4 / 16, 256, 0, stream>>>(xcbf, Wih[0], H2, hbf, Whh[0], H,
                                                 bih[0], bhh[0], gat, H4);
      k_cell<<<BH / 256, 256, 0, stream>>>(gat, cst, hst, hbf);
      k_mfma_skinny<<<H4 / 16, 256, 0, stream>>>(hbf, Wih[1], H, hbf + BH, Whh[1], H,
                                                 bih[1], bhh[1], gat, H4);
      k_cell<<<BH / 256, 256, 0, stream>>>(gat, cst + BH, hst + BH, hbf + BH);
      k_mfma_skinny<<<H4 / 16, 256, 0, stream>>>(hbf + BH, Wih[2], H, hbf + 2 * BH, Whh[2], H,
                                                 bih[2], bhh[2], gat, H4);
      k_cell2ln<<<B, 256, 0, stream>>>(gat, cst + 2 * BH, hst + 2 * BH, ong, onb,
                                       olall + (size_t)t * BH, hbf + 2 * BH);
      k_mfma_skinny<<<V / 16, 256, 0, stream>>>(olall + (size_t)t * BH, fcw, H,
                                                nullptr, nullptr, 0,
                                                fcb, nullptr, out + (size_t)t * V, T * V);
    }
    k_fin<<<768, 256, 0, stream>>>(hst, hst + 2 * BH, cst, out);
  }
}